// Round 3
// baseline (47945.102 us; speedup 1.0000x reference)
//
#include <hip/hip_runtime.h>
#include <cstdint>

// ---------------- problem dims ----------------
#define TB 8
#define TS 128
#define TDIN 768
#define TN 64
#define TD 128
#define TH 4
#define TMAXT 8

// ---------------- workspace layout (float offsets) ----------------
#define WS_WLAM 0            // 128*128 : diag(lam) @ dn_wo
#define WS_M    16384        // 128*128 : M = w_q @ w_k^T
#define WS_QK   32768        // B*S*128
#define WS_ACC  163840       // B*S*128
#define WS_HALT 294912       // u64[(S*8+t) slots * 8 batches], write-once per launch
#define WS_C    311296       // 128 x 520 combined chain matrix
#define C_LD    520

__device__ __forceinline__ float wsum64(float v) {
  v += __shfl_xor(v, 1);  v += __shfl_xor(v, 2);  v += __shfl_xor(v, 4);
  v += __shfl_xor(v, 8);  v += __shfl_xor(v, 16); v += __shfl_xor(v, 32);
  return v;
}
__device__ __forceinline__ float wmax64(float v) {
  v = fmaxf(v, __shfl_xor(v, 1));  v = fmaxf(v, __shfl_xor(v, 2));
  v = fmaxf(v, __shfl_xor(v, 4));  v = fmaxf(v, __shfl_xor(v, 8));
  v = fmaxf(v, __shfl_xor(v, 16)); v = fmaxf(v, __shfl_xor(v, 32));
  return v;
}

// ================= kernel 0: Wlam and M = w_q @ w_k^T =================
__global__ __launch_bounds__(256) void k0_prep(const float* __restrict__ w_q,
                                               const float* __restrict__ w_k,
                                               const float* __restrict__ dn_lam,
                                               const float* __restrict__ dn_wo,
                                               float* __restrict__ ws) {
  const int bx = blockIdx.x, tid = threadIdx.x;
  if (bx < 32) {
    int i = bx * 512 + tid;
    ws[WS_WLAM + i] = dn_lam[i >> 7] * dn_wo[i];
    i += 256;
    ws[WS_WLAM + i] = dn_lam[i >> 7] * dn_wo[i];
  } else {
    __shared__ float part[2][128];
    const int r0 = (bx - 32) * 4;
    const int c = tid & 127, half = tid >> 7;
    for (int rr = 0; rr < 4; ++rr) {
      const int k = r0 + rr;
      const float* wq = w_q + k * TD + half * 64;
      const float* wk = w_k + c * TD + half * 64;
      float p = 0.f;
      #pragma unroll 8
      for (int d = 0; d < 64; ++d) p = fmaf(wq[d], wk[d], p);
      part[half][c] = p;
      __syncthreads();
      if (tid < 128) ws[WS_M + k * TD + tid] = part[0][tid] + part[1][tid];
      __syncthreads();
    }
  }
}

// ================= kernel 0c: C = [w_v | w_v@dn_wk | w_v@dn_wv | w_v@w_gate | w_v@halt_w1 | w_v@dn_wb] =================
__device__ __forceinline__ float k0c_dot(const float* __restrict__ row,
                                         const float* __restrict__ Wcol, int stride) {
  float sAcc = 0.f;
  #pragma unroll 8
  for (int m = 0; m < TD; ++m) sAcc = fmaf(row[m], Wcol[m * stride], sAcc);
  return sAcc;
}

__global__ __launch_bounds__(256) void k0c_prep(const float* __restrict__ w_v,
                                                const float* __restrict__ dn_wk,
                                                const float* __restrict__ dn_wv,
                                                const float* __restrict__ w_gate,
                                                const float* __restrict__ halt_w1,
                                                const float* __restrict__ dn_wb,
                                                float* __restrict__ ws) {
  const int k = blockIdx.x, tid = threadIdx.x;
  __shared__ float row[TD];
  if (tid < TD) row[tid] = w_v[k * TD + tid];
  __syncthreads();
  float* Crow = ws + WS_C + (size_t)k * C_LD;
  #pragma unroll
  for (int pass = 0; pass < 2; ++pass) {
    const int c = tid + pass * 256;
    float val;
    if (c < 128)       val = row[c];
    else if (c < 256)  val = k0c_dot(row, dn_wk + (c - 128), TD);
    else if (c < 384)  val = k0c_dot(row, dn_wv + (c - 256), TD);
    else if (c < 448)  val = k0c_dot(row, w_gate + (c - 384), TN);
    else               val = k0c_dot(row, halt_w1 + (c - 448), 64);
    Crow[c] = val;
  }
  if (tid < 4) Crow[512 + tid] = k0c_dot(row, dn_wb + tid, TH);
}

// ================= kernel 1: qk_all[b][s] = LN(x) @ w_in @ M =================
__global__ __launch_bounds__(256) void k1_qk(const float* __restrict__ x,
                                             const float* __restrict__ ln_w,
                                             const float* __restrict__ ln_b,
                                             const float* __restrict__ w_in,
                                             float* __restrict__ ws) {
  const int bx = blockIdx.x, tid = threadIdx.x;
  const int b = bx >> 5;
  const int s0 = (bx & 31) * 4;
  const int wv = tid >> 6, lane = tid & 63;

  __shared__ float xn[4][TDIN];
  __shared__ float xp[4][TD];
  __shared__ float part[2][4][TD];
  __shared__ float red[4];

  for (int ss = 0; ss < 4; ++ss) {
    const float* xrow = x + ((size_t)(b * TS + s0 + ss)) * TDIN;
    float v0 = xrow[tid], v1 = xrow[tid + 256], v2 = xrow[tid + 512];
    float p = wsum64(v0 + v1 + v2);
    if (lane == 0) red[wv] = p;
    __syncthreads();
    const float mu = (red[0] + red[1] + red[2] + red[3]) * (1.f / 768.f);
    __syncthreads();
    const float d0 = v0 - mu, d1 = v1 - mu, d2 = v2 - mu;
    p = wsum64(d0 * d0 + d1 * d1 + d2 * d2);
    if (lane == 0) red[wv] = p;
    __syncthreads();
    const float var = (red[0] + red[1] + red[2] + red[3]) * (1.f / 768.f);
    const float rstd = 1.f / sqrtf(var + 1e-5f);
    xn[ss][tid]       = d0 * rstd * ln_w[tid]       + ln_b[tid];
    xn[ss][tid + 256] = d1 * rstd * ln_w[tid + 256] + ln_b[tid + 256];
    xn[ss][tid + 512] = d2 * rstd * ln_w[tid + 512] + ln_b[tid + 512];
    __syncthreads();
  }

  {
    const int d = tid & 127, j = tid >> 7;
    float a0 = 0.f, a1 = 0.f, a2 = 0.f, a3 = 0.f;
    const int kb = j * 384;
    #pragma unroll 4
    for (int k = 0; k < 384; ++k) {
      const float w = w_in[(kb + k) * TD + d];
      a0 = fmaf(xn[0][kb + k], w, a0);
      a1 = fmaf(xn[1][kb + k], w, a1);
      a2 = fmaf(xn[2][kb + k], w, a2);
      a3 = fmaf(xn[3][kb + k], w, a3);
    }
    part[j][0][d] = a0; part[j][1][d] = a1; part[j][2][d] = a2; part[j][3][d] = a3;
  }
  __syncthreads();
  if (tid < 128) {
    #pragma unroll
    for (int ss = 0; ss < 4; ++ss) xp[ss][tid] = part[0][ss][tid] + part[1][ss][tid];
  }
  __syncthreads();
  {
    const int c = tid & 127, j = tid >> 7;
    float a0 = 0.f, a1 = 0.f, a2 = 0.f, a3 = 0.f;
    const float* Mp = ws + WS_M;
    const int kb = j * 64;
    #pragma unroll 4
    for (int k = 0; k < 64; ++k) {
      const float m = Mp[(kb + k) * TD + c];
      a0 = fmaf(xp[0][kb + k], m, a0);
      a1 = fmaf(xp[1][kb + k], m, a1);
      a2 = fmaf(xp[2][kb + k], m, a2);
      a3 = fmaf(xp[3][kb + k], m, a3);
    }
    part[j][0][c] = a0; part[j][1][c] = a1; part[j][2][c] = a2; part[j][3][c] = a3;
  }
  __syncthreads();
  if (tid < 128) {
    #pragma unroll
    for (int ss = 0; ss < 4; ++ss)
      ws[WS_QK + (size_t)(b * TS + s0 + ss) * TD + tid] = part[0][ss][tid] + part[1][ss][tid];
  }
}

// ---------------- k2 helpers: per-wave column tiles ----------------
// GEMM/score/commit col split: w0:none, w1:16@0, w2:16@16, w3:16@32,
// w4:32@48 (shares SIMD0 with light wave0), w5:16@80, w6:16@96, w7:16@112.

template<int C0, int NC>
__device__ __forceinline__ void gemm_cols(const float* __restrict__ Wlam,
                                          const float (*S)[129], int l, float* G) {
  #pragma unroll
  for (int j = 0; j < NC; ++j) G[j] = 0.f;
  #pragma unroll 4
  for (int k = 0; k < 128; ++k) {
    const float a = S[l][k];                 // bank (l+k)%32 -> 2-way, free
    const float* wr = Wlam + k * TD + C0;    // wave-uniform -> scalar loads
    #pragma unroll
    for (int j = 0; j < NC; ++j) G[j] = fmaf(a, wr[j], G[j]);
  }
}

template<int C0, int NC>
__device__ __forceinline__ float score_cols(const float (*S)[129], int l,
                                            const float* sh_qk) {
  float sp = 0.f;
  #pragma unroll
  for (int j = 0; j < NC; ++j) sp = fmaf(S[l][C0 + j], sh_qk[C0 + j], sp);
  return sp;
}

template<int C0, int NC>
__device__ __forceinline__ float commit_cols(float (*S)[129], int l, const float* G,
                                             float g, float kh0, float kh1, float kh2, float kh3,
                                             const float (*sh_vo)[TD], const float (*sh_ko)[TD],
                                             const float* sh_qk) {
  float sp = 0.f;
  #pragma unroll
  for (int j = 0; j < NC; ++j) {
    const int c = C0 + j;
    float u = G[j];
    u += sh_vo[0][c] - kh0 * sh_ko[0][c];
    u += sh_vo[1][c] - kh1 * sh_ko[1][c];
    u += sh_vo[2][c] - kh2 * sh_ko[2][c];
    u += sh_vo[3][c] - kh3 * sh_ko[3][c];
    const float ns = (1.f - g) * S[l][c] + g * u;
    S[l][c] = ns;
    sp = fmaf(ns, sh_qk[c], sp);
  }
  return sp;
}

template<int C0, int NC>
__device__ __forceinline__ void store_cols(const float (*S)[129], int l,
                                           float* __restrict__ dst) {
  #pragma unroll
  for (int j = 0; j < NC; ++j) dst[l * TD + C0 + j] = S[l][C0 + j];
}

// ================= kernel 2: the recurrence (8 blocks, 512 thr, 1 per batch) =================
__global__ __launch_bounds__(512) void k2_main(
    const float* __restrict__ slot_memory,
    const float* __restrict__ b_gate,
    const float* __restrict__ halt_b1, const float* __restrict__ halt_w2,
    const float* __restrict__ halt_b2,
    const float* __restrict__ dn_bb,   const float* __restrict__ dn_wo,
    float* __restrict__ ws, float* __restrict__ out) {
  const int tid = threadIdx.x;
  const int b = blockIdx.x;
  const int l = tid & 63, wv = tid >> 6;

  __shared__ float S[TN][129];
  __shared__ float sh_scorepart[8][TN];
  __shared__ float sh_qk[TD];
  __shared__ float sh_rs[TD];
  __shared__ float sh_ro[TD];
  __shared__ float sh_gate[TN];
  __shared__ float sh_kn[TD];
  __shared__ float sh_v[TD];
  __shared__ float sh_beta[TH];
  __shared__ float sh_vo[TH][TD];
  __shared__ float sh_ko[TH][TD];
  __shared__ float sh_kh[TH][TN];
  __shared__ float sh_hl;
  __shared__ int   sh_break;

  unsigned long long* hslots = (unsigned long long*)(ws + WS_HALT);
  const float* Wlam = ws + WS_WLAM;
  const float* Cm = ws + WS_C;

  for (int i = tid; i < TN * TD; i += 512)
    S[i >> 7][i & 127] = slot_memory[i];

  float acc0 = 0.f, acc1 = 0.f, rem = 1.f;

  for (int s = 0; s < TS; ++s) {
    if (tid < TD) sh_qk[tid] = ws[WS_QK + (size_t)(b * TS + s) * TD + tid];
    if (wv == 0) { acc0 = 0.f; acc1 = 0.f; rem = 1.f; }
    __syncthreads();
    // PH_0: fresh score partials (new qk, current slots)
    {
      float sp = 0.f;
      switch (wv) {
        case 1: sp = score_cols<0, 16>(S, l, sh_qk); break;
        case 2: sp = score_cols<16, 16>(S, l, sh_qk); break;
        case 3: sp = score_cols<32, 16>(S, l, sh_qk); break;
        case 4: sp = score_cols<48, 32>(S, l, sh_qk); break;
        case 5: sp = score_cols<80, 16>(S, l, sh_qk); break;
        case 6: sp = score_cols<96, 16>(S, l, sh_qk); break;
        case 7: sp = score_cols<112, 16>(S, l, sh_qk); break;
        default: break;
      }
      if (wv) sh_scorepart[wv][l] = sp;
    }
    __syncthreads();

    for (int t = 0; t < TMAXT; ++t) {
      float G[32];
      // ---- PH_A: wave0 softmax+rs+poll; waves1-7 GEMM (S @ Wlam) ----
      if (wv == 0) {
        float sc = sh_scorepart[1][l] + sh_scorepart[2][l] + sh_scorepart[3][l]
                 + sh_scorepart[4][l] + sh_scorepart[5][l] + sh_scorepart[6][l]
                 + sh_scorepart[7][l];
        const float y = sc * 0.08838834764831845f;   // 1/sqrt(128)
        const float mx = wmax64(y);
        const float e = expf(y - mx);
        const float se = wsum64(e);
        const float a = e / se;                      // lane n holds attn[n]
        float r0 = 0.f, r1 = 0.f;
        #pragma unroll 8
        for (int n = 0; n < TN; ++n) {
          const float an = __shfl(a, n);
          r0 = fmaf(an, S[n][l], r0);
          r1 = fmaf(an, S[n][l + 64], r1);
        }
        sh_rs[l] = r0; sh_rs[l + 64] = r1;
        if (t >= 2) {
          if (l < 8) {
            const unsigned want = (unsigned)(s * 8 + t - 1);
            unsigned long long vv_;
            do {
              vv_ = __hip_atomic_load(&hslots[(size_t)want * 8 + l],
                                      __ATOMIC_RELAXED, __HIP_MEMORY_SCOPE_AGENT);
            } while ((unsigned)(vv_ >> 32) != want);
            float hv = __uint_as_float((unsigned)vv_);
            hv += __shfl_xor(hv, 1); hv += __shfl_xor(hv, 2); hv += __shfl_xor(hv, 4);
            if (l == 0) sh_break = (hv * 0.125f > 0.5f) ? 1 : 0;
          }
        } else if (l == 0) {
          sh_break = 0;
        }
      } else {
        switch (wv) {
          case 1: gemm_cols<0, 16>(Wlam, S, l, G); break;
          case 2: gemm_cols<16, 16>(Wlam, S, l, G); break;
          case 3: gemm_cols<32, 16>(Wlam, S, l, G); break;
          case 4: gemm_cols<48, 32>(Wlam, S, l, G); break;
          case 5: gemm_cols<80, 16>(Wlam, S, l, G); break;
          case 6: gemm_cols<96, 16>(Wlam, S, l, G); break;
          default: gemm_cols<112, 16>(Wlam, S, l, G); break;
        }
      }
      __syncthreads();                      // b1
      if (sh_break) break;

      // ---- PH_C: rs @ C (one col per thread) + inline finishing ----
      {
        float acc = 0.f;
        const float* cp = Cm + tid;
        #pragma unroll 8
        for (int k = 0; k < 128; ++k) acc = fmaf(sh_rs[k], cp[k * C_LD], acc);
        if (wv <= 1) {
          sh_ro[tid] = acc;                                   // ro cols 0..127
          if (wv == 0 && l < 4) {                             // beta cols 512..515
            float a2 = 0.f;
            const float* cb = Cm + 512 + l;
            #pragma unroll 8
            for (int k = 0; k < 128; ++k) a2 = fmaf(sh_rs[k], cb[k * C_LD], a2);
            sh_beta[l] = 2.f / (1.f + expf(-(a2 + dn_bb[l])));
          }
        } else if (wv <= 3) {                                 // k raw -> normalized
          const int d = tid - 128;
          float sq = acc * acc;
          sq += __shfl_xor(sq, 1); sq += __shfl_xor(sq, 2); sq += __shfl_xor(sq, 4);
          sq += __shfl_xor(sq, 8); sq += __shfl_xor(sq, 16);
          sh_kn[d] = acc / (sqrtf(sq) + 1e-6f);
        } else if (wv <= 5) {                                 // v
          sh_v[tid - 256] = acc;
        } else if (wv == 6) {                                 // gate
          sh_gate[l] = 1.f / (1.f + expf(-(acc + b_gate[l])));
        } else {                                              // halt
          const float t1 = fmaxf(acc + halt_b1[l], 0.f);
          const float z = wsum64(t1 * halt_w2[l]);
          if (l == 0) {
            const float hlv = 1.f / (1.f + expf(-(z + halt_b2[0])));
            sh_hl = hlv;
            if (t >= 1 && t <= 6) {
              const unsigned stamp = (unsigned)(s * 8 + t);
              const unsigned long long pv =
                  ((unsigned long long)stamp << 32) | (unsigned long long)__float_as_uint(hlv);
              __hip_atomic_store(&hslots[(size_t)stamp * 8 + b], pv,
                                 __ATOMIC_RELAXED, __HIP_MEMORY_SCOPE_AGENT);
            }
          }
        }
      }
      __syncthreads();                      // b2

      // ---- PH_E: vo/ko (dn_wo stream) + kh ----
      {
        const int h = tid >> 7, c = tid & 127;
        const float bh = sh_beta[h];
        float av = 0.f, ak = 0.f;
        const float* wop = dn_wo + (h * 32) * TD + c;
        #pragma unroll 8
        for (int i = 0; i < 32; ++i) {
          const float w = wop[i * TD];
          av = fmaf(sh_v[h * 32 + i], w, av);
          ak = fmaf(sh_kn[h * 32 + i], w, ak);
        }
        sh_vo[h][c] = bh * av;
        sh_ko[h][c] = bh * ak;
        if (tid < 256) {
          const int n = tid & 63, hh = (tid >> 6) & 3;
          float kk = 0.f;
          #pragma unroll 8
          for (int i = 0; i < 32; ++i) kk = fmaf(sh_kn[hh * 32 + i], S[n][hh * 32 + i], kk);
          sh_kh[hh][n] = kk;
        }
      }
      __syncthreads();                      // b3

      // ---- commit + next-tick score partials ----
      {
        const float g = sh_gate[l];
        const float kh0 = sh_kh[0][l], kh1 = sh_kh[1][l], kh2 = sh_kh[2][l], kh3 = sh_kh[3][l];
        float sp = 0.f;
        switch (wv) {
          case 1: sp = commit_cols<0, 16>(S, l, G, g, kh0, kh1, kh2, kh3, sh_vo, sh_ko, sh_qk); break;
          case 2: sp = commit_cols<16, 16>(S, l, G, g, kh0, kh1, kh2, kh3, sh_vo, sh_ko, sh_qk); break;
          case 3: sp = commit_cols<32, 16>(S, l, G, g, kh0, kh1, kh2, kh3, sh_vo, sh_ko, sh_qk); break;
          case 4: sp = commit_cols<48, 32>(S, l, G, g, kh0, kh1, kh2, kh3, sh_vo, sh_ko, sh_qk); break;
          case 5: sp = commit_cols<80, 16>(S, l, G, g, kh0, kh1, kh2, kh3, sh_vo, sh_ko, sh_qk); break;
          case 6: sp = commit_cols<96, 16>(S, l, G, g, kh0, kh1, kh2, kh3, sh_vo, sh_ko, sh_qk); break;
          case 7: sp = commit_cols<112, 16>(S, l, G, g, kh0, kh1, kh2, kh3, sh_vo, sh_ko, sh_qk); break;
          default: break;
        }
        if (wv) {
          sh_scorepart[wv][l] = sp;
        } else {
          acc0 += rem * sh_ro[l];
          acc1 += rem * sh_ro[l + 64];
          if (t < TMAXT - 1) rem *= (1.f - sh_hl);
        }
      }
      __syncthreads();                      // b4
    }  // ticks

    if (wv == 0) {
      ws[WS_ACC + (size_t)(b * TS + s) * TD + l] = acc0;
      ws[WS_ACC + (size_t)(b * TS + s) * TD + l + 64] = acc1;
    }
  }  // steps

  {
    float* dst = out + (size_t)TB * TS * TDIN + (size_t)b * TN * TD;
    switch (wv) {
      case 1: store_cols<0, 16>(S, l, dst); break;
      case 2: store_cols<16, 16>(S, l, dst); break;
      case 3: store_cols<32, 16>(S, l, dst); break;
      case 4: store_cols<48, 32>(S, l, dst); break;
      case 5: store_cols<80, 16>(S, l, dst); break;
      case 6: store_cols<96, 16>(S, l, dst); break;
      case 7: store_cols<112, 16>(S, l, dst); break;
      default: break;
    }
  }
}

// ================= kernel 3: outs = acc_all @ w_out =================
__global__ __launch_bounds__(256) void k3_out(const float* __restrict__ w_out,
                                              const float* __restrict__ ws,
                                              float* __restrict__ out) {
  const int bx = blockIdx.x, tid = threadIdx.x;
  const int r0 = bx * 8;
  __shared__ float a8[8][TD];
  for (int i = tid; i < 8 * TD; i += 256)
    a8[i >> 7][i & 127] = ws[WS_ACC + (size_t)r0 * TD + i];
  __syncthreads();
  float p[8][3];
  #pragma unroll
  for (int ss = 0; ss < 8; ++ss) { p[ss][0] = 0.f; p[ss][1] = 0.f; p[ss][2] = 0.f; }
  #pragma unroll 2
  for (int d = 0; d < TD; ++d) {
    const float w0 = w_out[d * TDIN + tid];
    const float w1 = w_out[d * TDIN + tid + 256];
    const float w2 = w_out[d * TDIN + tid + 512];
    #pragma unroll
    for (int ss = 0; ss < 8; ++ss) {
      const float a = a8[ss][d];
      p[ss][0] = fmaf(a, w0, p[ss][0]);
      p[ss][1] = fmaf(a, w1, p[ss][1]);
      p[ss][2] = fmaf(a, w2, p[ss][2]);
    }
  }
  #pragma unroll
  for (int ss = 0; ss < 8; ++ss) {
    out[(size_t)(r0 + ss) * TDIN + tid]       = p[ss][0];
    out[(size_t)(r0 + ss) * TDIN + tid + 256] = p[ss][1];
    out[(size_t)(r0 + ss) * TDIN + tid + 512] = p[ss][2];
  }
}

// ================= host launcher =================
extern "C" void kernel_launch(void* const* d_in, const int* in_sizes, int n_in,
                              void* d_out, int out_size, void* d_ws, size_t ws_size,
                              hipStream_t stream) {
  (void)in_sizes; (void)n_in; (void)out_size; (void)ws_size;
  const float* x           = (const float*)d_in[0];
  const float* slot_memory = (const float*)d_in[1];
  const float* ln_w        = (const float*)d_in[2];
  const float* ln_b        = (const float*)d_in[3];
  const float* w_in        = (const float*)d_in[4];
  const float* w_q         = (const float*)d_in[5];
  const float* w_k         = (const float*)d_in[6];
  const float* w_v         = (const float*)d_in[7];
  const float* w_gate      = (const float*)d_in[8];
  const float* b_gate      = (const float*)d_in[9];
  const float* halt_w1     = (const float*)d_in[10];
  const float* halt_b1     = (const float*)d_in[11];
  const float* halt_w2     = (const float*)d_in[12];
  const float* halt_b2     = (const float*)d_in[13];
  const float* w_out       = (const float*)d_in[14];
  const float* dn_wk       = (const float*)d_in[15];
  const float* dn_wv       = (const float*)d_in[16];
  const float* dn_wb       = (const float*)d_in[17];
  const float* dn_bb       = (const float*)d_in[18];
  const float* dn_lam      = (const float*)d_in[19];
  const float* dn_wo       = (const float*)d_in[20];
  float* ws  = (float*)d_ws;
  float* out = (float*)d_out;

  k0_prep<<<dim3(64), dim3(256), 0, stream>>>(w_q, w_k, dn_lam, dn_wo, ws);
  k0c_prep<<<dim3(128), dim3(256), 0, stream>>>(w_v, dn_wk, dn_wv, w_gate, halt_w1, dn_wb, ws);
  k1_qk<<<dim3(256), dim3(256), 0, stream>>>(x, ln_w, ln_b, w_in, ws);
  k2_main<<<dim3(TB), dim3(512), 0, stream>>>(slot_memory, b_gate,
                                              halt_b1, halt_w2, halt_b2,
                                              dn_bb, dn_wo, ws, out);
  k3_out<<<dim3(128), dim3(256), 0, stream>>>(w_out, ws, out);
}

// Round 4
// 27661.026 us; speedup vs baseline: 1.7333x; 1.7333x over previous
//
#include <hip/hip_runtime.h>
#include <cstdint>

// ---------------- problem dims ----------------
#define TB 8
#define TS 128
#define TDIN 768
#define TN 64
#define TD 128
#define TH 4
#define TMAXT 8

// ---------------- workspace layout (float offsets) ----------------
#define WS_WLAM 0            // 128*128 : diag(lam) @ dn_wo
#define WS_M    16384        // 128*128 : M = w_q @ w_k^T
#define WS_QK   32768        // B*S*128
#define WS_ACC  163840       // B*S*128
#define WS_HALT 294912       // u64[stamp*8+b], write-once per launch
#define WS_C    311296       // 128 x 512 combined chain matrix, row-major [k][col]
#define WS_BW   376832       // 128 x 4 : w_v @ dn_wb

__device__ __forceinline__ float wsum64(float v) {
  v += __shfl_xor(v, 1);  v += __shfl_xor(v, 2);  v += __shfl_xor(v, 4);
  v += __shfl_xor(v, 8);  v += __shfl_xor(v, 16); v += __shfl_xor(v, 32);
  return v;
}
__device__ __forceinline__ float wmax64(float v) {
  v = fmaxf(v, __shfl_xor(v, 1));  v = fmaxf(v, __shfl_xor(v, 2));
  v = fmaxf(v, __shfl_xor(v, 4));  v = fmaxf(v, __shfl_xor(v, 8));
  v = fmaxf(v, __shfl_xor(v, 16)); v = fmaxf(v, __shfl_xor(v, 32));
  return v;
}

// ================= kernel 0: Wlam and M = w_q @ w_k^T =================
__global__ __launch_bounds__(256) void k0_prep(const float* __restrict__ w_q,
                                               const float* __restrict__ w_k,
                                               const float* __restrict__ dn_lam,
                                               const float* __restrict__ dn_wo,
                                               float* __restrict__ ws) {
  const int bx = blockIdx.x, tid = threadIdx.x;
  if (bx < 32) {
    int i = bx * 512 + tid;
    ws[WS_WLAM + i] = dn_lam[i >> 7] * dn_wo[i];
    i += 256;
    ws[WS_WLAM + i] = dn_lam[i >> 7] * dn_wo[i];
  } else {
    __shared__ float part[2][128];
    const int r0 = (bx - 32) * 4;
    const int c = tid & 127, half = tid >> 7;
    for (int rr = 0; rr < 4; ++rr) {
      const int k = r0 + rr;
      const float* wq = w_q + k * TD + half * 64;
      const float* wk = w_k + c * TD + half * 64;
      float p = 0.f;
      #pragma unroll 8
      for (int d = 0; d < 64; ++d) p = fmaf(wq[d], wk[d], p);
      part[half][c] = p;
      __syncthreads();
      if (tid < 128) ws[WS_M + k * TD + tid] = part[0][tid] + part[1][tid];
      __syncthreads();
    }
  }
}

// ====== kernel 0c: C[k][col] (128x512) + BetaW = w_v@dn_wb (128x4) ======
__device__ __forceinline__ float k0c_dot(const float* __restrict__ row,
                                         const float* __restrict__ Wcol, int stride) {
  float sAcc = 0.f;
  #pragma unroll 8
  for (int m = 0; m < TD; ++m) sAcc = fmaf(row[m], Wcol[m * stride], sAcc);
  return sAcc;
}

__global__ __launch_bounds__(256) void k0c_prep(const float* __restrict__ w_v,
                                                const float* __restrict__ dn_wk,
                                                const float* __restrict__ dn_wv,
                                                const float* __restrict__ w_gate,
                                                const float* __restrict__ halt_w1,
                                                const float* __restrict__ dn_wb,
                                                float* __restrict__ ws) {
  const int k = blockIdx.x, tid = threadIdx.x;
  __shared__ float row[TD];
  if (tid < TD) row[tid] = w_v[k * TD + tid];
  __syncthreads();
  float* Crow = ws + WS_C + (size_t)k * 512;
  #pragma unroll
  for (int pass = 0; pass < 2; ++pass) {
    const int c = tid + pass * 256;
    float val;
    if (c < 128)       val = row[c];
    else if (c < 256)  val = k0c_dot(row, dn_wk + (c - 128), TD);
    else if (c < 384)  val = k0c_dot(row, dn_wv + (c - 256), TD);
    else if (c < 448)  val = k0c_dot(row, w_gate + (c - 384), TN);
    else               val = k0c_dot(row, halt_w1 + (c - 448), 64);
    Crow[c] = val;
  }
  if (tid < 4) ws[WS_BW + k * TH + tid] = k0c_dot(row, dn_wb + tid, TH);
}

// ================= kernel 1: qk_all[b][s] = LN(x) @ w_in @ M =================
__global__ __launch_bounds__(256) void k1_qk(const float* __restrict__ x,
                                             const float* __restrict__ ln_w,
                                             const float* __restrict__ ln_b,
                                             const float* __restrict__ w_in,
                                             float* __restrict__ ws) {
  const int bx = blockIdx.x, tid = threadIdx.x;
  const int b = bx >> 5;
  const int s0 = (bx & 31) * 4;
  const int wv = tid >> 6, lane = tid & 63;

  __shared__ float xn[4][TDIN];
  __shared__ float xp[4][TD];
  __shared__ float part[2][4][TD];
  __shared__ float red[4];

  for (int ss = 0; ss < 4; ++ss) {
    const float* xrow = x + ((size_t)(b * TS + s0 + ss)) * TDIN;
    float v0 = xrow[tid], v1 = xrow[tid + 256], v2 = xrow[tid + 512];
    float p = wsum64(v0 + v1 + v2);
    if (lane == 0) red[wv] = p;
    __syncthreads();
    const float mu = (red[0] + red[1] + red[2] + red[3]) * (1.f / 768.f);
    __syncthreads();
    const float d0 = v0 - mu, d1 = v1 - mu, d2 = v2 - mu;
    p = wsum64(d0 * d0 + d1 * d1 + d2 * d2);
    if (lane == 0) red[wv] = p;
    __syncthreads();
    const float var = (red[0] + red[1] + red[2] + red[3]) * (1.f / 768.f);
    const float rstd = 1.f / sqrtf(var + 1e-5f);
    xn[ss][tid]       = d0 * rstd * ln_w[tid]       + ln_b[tid];
    xn[ss][tid + 256] = d1 * rstd * ln_w[tid + 256] + ln_b[tid + 256];
    xn[ss][tid + 512] = d2 * rstd * ln_w[tid + 512] + ln_b[tid + 512];
    __syncthreads();
  }

  {
    const int d = tid & 127, j = tid >> 7;
    float a0 = 0.f, a1 = 0.f, a2 = 0.f, a3 = 0.f;
    const int kb = j * 384;
    #pragma unroll 4
    for (int k = 0; k < 384; ++k) {
      const float w = w_in[(kb + k) * TD + d];
      a0 = fmaf(xn[0][kb + k], w, a0);
      a1 = fmaf(xn[1][kb + k], w, a1);
      a2 = fmaf(xn[2][kb + k], w, a2);
      a3 = fmaf(xn[3][kb + k], w, a3);
    }
    part[j][0][d] = a0; part[j][1][d] = a1; part[j][2][d] = a2; part[j][3][d] = a3;
  }
  __syncthreads();
  if (tid < 128) {
    #pragma unroll
    for (int ss = 0; ss < 4; ++ss) xp[ss][tid] = part[0][ss][tid] + part[1][ss][tid];
  }
  __syncthreads();
  {
    const int c = tid & 127, j = tid >> 7;
    float a0 = 0.f, a1 = 0.f, a2 = 0.f, a3 = 0.f;
    const float* Mp = ws + WS_M;
    const int kb = j * 64;
    #pragma unroll 4
    for (int k = 0; k < 64; ++k) {
      const float m = Mp[(kb + k) * TD + c];
      a0 = fmaf(xp[0][kb + k], m, a0);
      a1 = fmaf(xp[1][kb + k], m, a1);
      a2 = fmaf(xp[2][kb + k], m, a2);
      a3 = fmaf(xp[3][kb + k], m, a3);
    }
    part[j][0][c] = a0; part[j][1][c] = a1; part[j][2][c] = a2; part[j][3][c] = a3;
  }
  __syncthreads();
  if (tid < 128) {
    #pragma unroll
    for (int ss = 0; ss < 4; ++ss)
      ws[WS_QK + (size_t)(b * TS + s0 + ss) * TD + tid] = part[0][ss][tid] + part[1][ss][tid];
  }
}

// ---------------- k2 helpers ----------------
// GEMM/score/commit col split (all multiples of 4; wave0 has none — it runs the
// serial chain): w1:20@0, w2:20@20, w3:20@40, w4:16@60, w5:16@76, w6:16@92, w7:20@108.

template<int C0, int NC>
__device__ __forceinline__ void gemm_lds(const float* __restrict__ shW,
                                         const float (*S)[129], int l, float* G) {
  #pragma unroll
  for (int j = 0; j < NC; ++j) G[j] = 0.f;
  #pragma unroll 4
  for (int k = 0; k < 128; ++k) {
    const float a = S[l][k];                         // bank (l+k)%32 -> 2-way free
    const float4* wrow = (const float4*)(&shW[k * TD + C0]);  // uniform -> broadcast
    #pragma unroll
    for (int jq = 0; jq < NC / 4; ++jq) {
      const float4 w = wrow[jq];
      G[4*jq+0] = fmaf(a, w.x, G[4*jq+0]);
      G[4*jq+1] = fmaf(a, w.y, G[4*jq+1]);
      G[4*jq+2] = fmaf(a, w.z, G[4*jq+2]);
      G[4*jq+3] = fmaf(a, w.w, G[4*jq+3]);
    }
  }
}

template<int C0, int NC>
__device__ __forceinline__ float score_cols(const float (*S)[129], int l,
                                            const float* sh_qk) {
  float sp = 0.f;
  #pragma unroll
  for (int jq = 0; jq < NC / 4; ++jq) {
    const int c = C0 + 4 * jq;
    const float4 qv = *(const float4*)(&sh_qk[c]);
    sp = fmaf(S[l][c+0], qv.x, sp);
    sp = fmaf(S[l][c+1], qv.y, sp);
    sp = fmaf(S[l][c+2], qv.z, sp);
    sp = fmaf(S[l][c+3], qv.w, sp);
  }
  return sp;
}

template<int C0, int NC>
__device__ __forceinline__ float commit_cols(float (*S)[129], int l, const float* G,
                                             float g, float kh0, float kh1, float kh2, float kh3,
                                             const float (*sh_vo)[TD], const float (*sh_ko)[TD],
                                             const float* sh_qk) {
  float sp = 0.f;
  const float omg = 1.f - g;
  #pragma unroll
  for (int jq = 0; jq < NC / 4; ++jq) {
    const int c = C0 + 4 * jq;
    const float4 v0 = *(const float4*)(&sh_vo[0][c]);
    const float4 v1 = *(const float4*)(&sh_vo[1][c]);
    const float4 v2 = *(const float4*)(&sh_vo[2][c]);
    const float4 v3 = *(const float4*)(&sh_vo[3][c]);
    const float4 k0 = *(const float4*)(&sh_ko[0][c]);
    const float4 k1 = *(const float4*)(&sh_ko[1][c]);
    const float4 k2 = *(const float4*)(&sh_ko[2][c]);
    const float4 k3 = *(const float4*)(&sh_ko[3][c]);
    const float4 qv = *(const float4*)(&sh_qk[c]);
    float u;
    u = G[4*jq+0] + (v0.x - kh0*k0.x) + (v1.x - kh1*k1.x) + (v2.x - kh2*k2.x) + (v3.x - kh3*k3.x);
    { const float ns = omg * S[l][c+0] + g * u; S[l][c+0] = ns; sp = fmaf(ns, qv.x, sp); }
    u = G[4*jq+1] + (v0.y - kh0*k0.y) + (v1.y - kh1*k1.y) + (v2.y - kh2*k2.y) + (v3.y - kh3*k3.y);
    { const float ns = omg * S[l][c+1] + g * u; S[l][c+1] = ns; sp = fmaf(ns, qv.y, sp); }
    u = G[4*jq+2] + (v0.z - kh0*k0.z) + (v1.z - kh1*k1.z) + (v2.z - kh2*k2.z) + (v3.z - kh3*k3.z);
    { const float ns = omg * S[l][c+2] + g * u; S[l][c+2] = ns; sp = fmaf(ns, qv.z, sp); }
    u = G[4*jq+3] + (v0.w - kh0*k0.w) + (v1.w - kh1*k1.w) + (v2.w - kh2*k2.w) + (v3.w - kh3*k3.w);
    { const float ns = omg * S[l][c+3] + g * u; S[l][c+3] = ns; sp = fmaf(ns, qv.w, sp); }
  }
  return sp;
}

template<int C0, int NC>
__device__ __forceinline__ void store_cols(const float (*S)[129], int l,
                                           float* __restrict__ dst) {
  #pragma unroll
  for (int j = 0; j < NC; ++j) dst[l * TD + C0 + j] = S[l][C0 + j];
}

// ================= kernel 2: recurrence (8 blocks x 512, 1 per batch) =================
__global__ __launch_bounds__(512, 2) void k2_main(
    const float* __restrict__ slot_memory,
    const float* __restrict__ b_gate,
    const float* __restrict__ halt_b1, const float* __restrict__ halt_w2,
    const float* __restrict__ halt_b2,
    const float* __restrict__ dn_bb,   const float* __restrict__ dn_wo,
    float* __restrict__ ws, float* __restrict__ out) {
  const int tid = threadIdx.x;
  const int b = blockIdx.x;
  const int l = tid & 63, wv = tid >> 6;

  __shared__ float shW[TD * TD];        // 64 KB : Wlam, LDS-resident
  __shared__ float S[TN][129];          // 33 KB : slots (b32-conflict-free)
  __shared__ float sh_scorepart[8][TN];
  __shared__ float sh_qk[TD];
  __shared__ float sh_rs[TD];
  __shared__ float sh_ro[TD];
  __shared__ float sh_gate[TN];
  __shared__ float sh_kn[TD];
  __shared__ float sh_v[TD];
  __shared__ float sh_beta[TH];
  __shared__ float sh_vo[TH][TD];
  __shared__ float sh_ko[TH][TD];
  __shared__ float sh_kh[TH][TN];
  __shared__ float sh_bw[TD * TH];      // 2 KB : w_v@dn_wb
  __shared__ float sh_hb1[64], sh_hw2[64], sh_bg[64], sh_bb[TH];
  __shared__ float sh_hl, sh_hb2;
  __shared__ int   sh_break;

  unsigned long long* hslots = (unsigned long long*)(ws + WS_HALT);

  // ---- one-time preloads (the only bulk global reads in this kernel) ----
  for (int i = tid; i < TD * TD; i += 512) shW[i] = ws[WS_WLAM + i];
  for (int i = tid; i < TN * TD; i += 512) S[i >> 7][i & 127] = slot_memory[i];
  for (int i = tid; i < TD * TH; i += 512) sh_bw[i] = ws[WS_BW + i];
  if (tid < 64) { sh_hb1[tid] = halt_b1[tid]; sh_hw2[tid] = halt_w2[tid]; sh_bg[tid] = b_gate[tid]; }
  if (tid < TH) sh_bb[tid] = dn_bb[tid];
  if (tid == 0) sh_hb2 = halt_b2[0];

  float creg[128];                      // this thread's column of C, register-resident
  {
    const float* cp = ws + WS_C + tid;
    #pragma unroll
    for (int k = 0; k < 128; ++k) creg[k] = cp[k * 512];
  }
  float wo_reg[32];                     // dn_wo[h*32..h*32+32][c], register-resident
  {
    const int h = tid >> 7, c = tid & 127;
    const float* wp = dn_wo + (h * 32) * TD + c;
    #pragma unroll
    for (int i = 0; i < 32; ++i) wo_reg[i] = wp[i * TD];
  }
  __syncthreads();

  float acc0 = 0.f, acc1 = 0.f, rem = 1.f;  // wave0 state

  for (int s = 0; s < TS; ++s) {
    if (tid < TD) sh_qk[tid] = ws[WS_QK + (size_t)(b * TS + s) * TD + tid];
    if (wv == 0) { acc0 = 0.f; acc1 = 0.f; rem = 1.f; }
    __syncthreads();
    // PH_0: fresh score partials (new qk, current slots)
    {
      float sp = 0.f;
      switch (wv) {
        case 1: sp = score_cols<0, 20>(S, l, sh_qk); break;
        case 2: sp = score_cols<20, 20>(S, l, sh_qk); break;
        case 3: sp = score_cols<40, 20>(S, l, sh_qk); break;
        case 4: sp = score_cols<60, 16>(S, l, sh_qk); break;
        case 5: sp = score_cols<76, 16>(S, l, sh_qk); break;
        case 6: sp = score_cols<92, 16>(S, l, sh_qk); break;
        case 7: sp = score_cols<108, 20>(S, l, sh_qk); break;
        default: break;
      }
      if (wv) sh_scorepart[wv][l] = sp;
    }
    __syncthreads();

    for (int t = 0; t < TMAXT; ++t) {
      float G[20];
      // ---- PH_A: wave0 softmax+rs+poll; waves1-7 GEMM S@Wlam (LDS weights) ----
      if (wv == 0) {
        float sc = sh_scorepart[1][l] + sh_scorepart[2][l] + sh_scorepart[3][l]
                 + sh_scorepart[4][l] + sh_scorepart[5][l] + sh_scorepart[6][l]
                 + sh_scorepart[7][l];
        const float y = sc * 0.08838834764831845f;   // 1/sqrt(128)
        const float mx = wmax64(y);
        const float e = expf(y - mx);
        const float se = wsum64(e);
        const float a = e / se;                      // lane n holds attn[n]
        float r0 = 0.f, r1 = 0.f;
        #pragma unroll 8
        for (int n = 0; n < TN; ++n) {
          const float an = __shfl(a, n);
          r0 = fmaf(an, S[n][l], r0);
          r1 = fmaf(an, S[n][l + 64], r1);
        }
        sh_rs[l] = r0; sh_rs[l + 64] = r1;
        if (t >= 2) {
          if (l < 8) {
            const unsigned want = (unsigned)(s * 8 + t - 1);
            unsigned long long vv_;
            do {
              vv_ = __hip_atomic_load(&hslots[(size_t)want * 8 + l],
                                      __ATOMIC_RELAXED, __HIP_MEMORY_SCOPE_AGENT);
            } while ((unsigned)(vv_ >> 32) != want);
            float hv = __uint_as_float((unsigned)vv_);
            hv += __shfl_xor(hv, 1); hv += __shfl_xor(hv, 2); hv += __shfl_xor(hv, 4);
            if (l == 0) sh_break = (hv * 0.125f > 0.5f) ? 1 : 0;
          }
        } else if (l == 0) {
          sh_break = 0;
        }
      } else {
        switch (wv) {
          case 1: gemm_lds<0, 20>(shW, S, l, G); break;
          case 2: gemm_lds<20, 20>(shW, S, l, G); break;
          case 3: gemm_lds<40, 20>(shW, S, l, G); break;
          case 4: gemm_lds<60, 16>(shW, S, l, G); break;
          case 5: gemm_lds<76, 16>(shW, S, l, G); break;
          case 6: gemm_lds<92, 16>(shW, S, l, G); break;
          default: gemm_lds<108, 20>(shW, S, l, G); break;
        }
      }
      __syncthreads();                      // b1
      if (sh_break) break;

      // ---- PH_C: rs @ C via register column + inline finishing ----
      {
        float a0 = 0.f, a1 = 0.f, a2 = 0.f, a3 = 0.f;
        #pragma unroll
        for (int kq = 0; kq < 32; ++kq) {
          const float4 r4 = *(const float4*)(&sh_rs[4 * kq]);
          a0 = fmaf(r4.x, creg[4*kq+0], a0);
          a1 = fmaf(r4.y, creg[4*kq+1], a1);
          a2 = fmaf(r4.z, creg[4*kq+2], a2);
          a3 = fmaf(r4.w, creg[4*kq+3], a3);
        }
        const float acc = (a0 + a1) + (a2 + a3);
        if (wv == 0) {
          sh_ro[l] = acc;
          if (l < 4) {                         // beta from LDS BetaW table
            float bacc = 0.f;
            #pragma unroll 8
            for (int k = 0; k < 128; ++k) bacc = fmaf(sh_rs[k], sh_bw[k * TH + l], bacc);
            sh_beta[l] = 2.f / (1.f + expf(-(bacc + sh_bb[l])));
          }
        } else if (wv == 1) {
          sh_ro[64 + l] = acc;
        } else if (wv == 2 || wv == 3) {       // k raw -> per-head normalized
          const int d = (wv - 2) * 64 + l;
          float sq = acc * acc;
          sq += __shfl_xor(sq, 1); sq += __shfl_xor(sq, 2); sq += __shfl_xor(sq, 4);
          sq += __shfl_xor(sq, 8); sq += __shfl_xor(sq, 16);
          sh_kn[d] = acc / (sqrtf(sq) + 1e-6f);
        } else if (wv == 4) {
          sh_v[l] = acc;
        } else if (wv == 5) {
          sh_v[64 + l] = acc;
        } else if (wv == 6) {
          sh_gate[l] = 1.f / (1.f + expf(-(acc + sh_bg[l])));
        } else {                               // halt + publish
          const float t1 = fmaxf(acc + sh_hb1[l], 0.f);
          const float z = wsum64(t1 * sh_hw2[l]);
          if (l == 0) {
            const float hlv = 1.f / (1.f + expf(-(z + sh_hb2)));
            sh_hl = hlv;
            if (t >= 1 && t <= 6) {
              const unsigned stamp = (unsigned)(s * 8 + t);
              const unsigned long long pv =
                  ((unsigned long long)stamp << 32) | (unsigned long long)__float_as_uint(hlv);
              __hip_atomic_store(&hslots[(size_t)stamp * 8 + b], pv,
                                 __ATOMIC_RELAXED, __HIP_MEMORY_SCOPE_AGENT);
            }
          }
        }
      }
      __syncthreads();                      // b2

      // ---- PH_E: vo/ko via register wo slice + kh ----
      {
        const int h = tid >> 7;
        const float bh = sh_beta[h];
        float av = 0.f, ak = 0.f;
        #pragma unroll
        for (int iq = 0; iq < 8; ++iq) {
          const float4 vvv = *(const float4*)(&sh_v[h * 32 + 4 * iq]);
          const float4 kkk = *(const float4*)(&sh_kn[h * 32 + 4 * iq]);
          av = fmaf(vvv.x, wo_reg[4*iq+0], av);
          av = fmaf(vvv.y, wo_reg[4*iq+1], av);
          av = fmaf(vvv.z, wo_reg[4*iq+2], av);
          av = fmaf(vvv.w, wo_reg[4*iq+3], av);
          ak = fmaf(kkk.x, wo_reg[4*iq+0], ak);
          ak = fmaf(kkk.y, wo_reg[4*iq+1], ak);
          ak = fmaf(kkk.z, wo_reg[4*iq+2], ak);
          ak = fmaf(kkk.w, wo_reg[4*iq+3], ak);
        }
        const int c = tid & 127;
        sh_vo[h][c] = bh * av;
        sh_ko[h][c] = bh * ak;
        if (tid < 256) {                       // kh[hh][n], hh = wave, n = lane
          const int n = l, hh = wv;
          float kk2 = 0.f;
          #pragma unroll
          for (int iq = 0; iq < 8; ++iq) {
            const float4 kv = *(const float4*)(&sh_kn[hh * 32 + 4 * iq]);
            kk2 = fmaf(kv.x, S[n][hh * 32 + 4 * iq + 0], kk2);
            kk2 = fmaf(kv.y, S[n][hh * 32 + 4 * iq + 1], kk2);
            kk2 = fmaf(kv.z, S[n][hh * 32 + 4 * iq + 2], kk2);
            kk2 = fmaf(kv.w, S[n][hh * 32 + 4 * iq + 3], kk2);
          }
          sh_kh[hh][n] = kk2;
        }
      }
      __syncthreads();                      // b3

      // ---- commit + next-tick score partials ----
      {
        const float g = sh_gate[l];
        const float kh0 = sh_kh[0][l], kh1 = sh_kh[1][l], kh2 = sh_kh[2][l], kh3 = sh_kh[3][l];
        float sp = 0.f;
        switch (wv) {
          case 1: sp = commit_cols<0, 20>(S, l, G, g, kh0, kh1, kh2, kh3, sh_vo, sh_ko, sh_qk); break;
          case 2: sp = commit_cols<20, 20>(S, l, G, g, kh0, kh1, kh2, kh3, sh_vo, sh_ko, sh_qk); break;
          case 3: sp = commit_cols<40, 20>(S, l, G, g, kh0, kh1, kh2, kh3, sh_vo, sh_ko, sh_qk); break;
          case 4: sp = commit_cols<60, 16>(S, l, G, g, kh0, kh1, kh2, kh3, sh_vo, sh_ko, sh_qk); break;
          case 5: sp = commit_cols<76, 16>(S, l, G, g, kh0, kh1, kh2, kh3, sh_vo, sh_ko, sh_qk); break;
          case 6: sp = commit_cols<92, 16>(S, l, G, g, kh0, kh1, kh2, kh3, sh_vo, sh_ko, sh_qk); break;
          case 7: sp = commit_cols<108, 20>(S, l, G, g, kh0, kh1, kh2, kh3, sh_vo, sh_ko, sh_qk); break;
          default: break;
        }
        if (wv) {
          sh_scorepart[wv][l] = sp;
        } else {
          acc0 += rem * sh_ro[l];
          acc1 += rem * sh_ro[l + 64];
          if (t < TMAXT - 1) rem *= (1.f - sh_hl);
        }
      }
      __syncthreads();                      // b4
    }  // ticks

    if (wv == 0) {
      ws[WS_ACC + (size_t)(b * TS + s) * TD + l] = acc0;
      ws[WS_ACC + (size_t)(b * TS + s) * TD + l + 64] = acc1;
    }
  }  // steps

  {
    float* dst = out + (size_t)TB * TS * TDIN + (size_t)b * TN * TD;
    switch (wv) {
      case 1: store_cols<0, 20>(S, l, dst); break;
      case 2: store_cols<20, 20>(S, l, dst); break;
      case 3: store_cols<40, 20>(S, l, dst); break;
      case 4: store_cols<60, 16>(S, l, dst); break;
      case 5: store_cols<76, 16>(S, l, dst); break;
      case 6: store_cols<92, 16>(S, l, dst); break;
      case 7: store_cols<108, 20>(S, l, dst); break;
      default: break;
    }
  }
}

// ================= kernel 3: outs = acc_all @ w_out =================
__global__ __launch_bounds__(256) void k3_out(const float* __restrict__ w_out,
                                              const float* __restrict__ ws,
                                              float* __restrict__ out) {
  const int bx = blockIdx.x, tid = threadIdx.x;
  const int r0 = bx * 8;
  __shared__ float a8[8][TD];
  for (int i = tid; i < 8 * TD; i += 256)
    a8[i >> 7][i & 127] = ws[WS_ACC + (size_t)r0 * TD + i];
  __syncthreads();
  float p[8][3];
  #pragma unroll
  for (int ss = 0; ss < 8; ++ss) { p[ss][0] = 0.f; p[ss][1] = 0.f; p[ss][2] = 0.f; }
  #pragma unroll 2
  for (int d = 0; d < TD; ++d) {
    const float w0 = w_out[d * TDIN + tid];
    const float w1 = w_out[d * TDIN + tid + 256];
    const float w2 = w_out[d * TDIN + tid + 512];
    #pragma unroll
    for (int ss = 0; ss < 8; ++ss) {
      const float a = a8[ss][d];
      p[ss][0] = fmaf(a, w0, p[ss][0]);
      p[ss][1] = fmaf(a, w1, p[ss][1]);
      p[ss][2] = fmaf(a, w2, p[ss][2]);
    }
  }
  #pragma unroll
  for (int ss = 0; ss < 8; ++ss) {
    out[(size_t)(r0 + ss) * TDIN + tid]       = p[ss][0];
    out[(size_t)(r0 + ss) * TDIN + tid + 256] = p[ss][1];
    out[(size_t)(r0 + ss) * TDIN + tid + 512] = p[ss][2];
  }
}

// ================= host launcher =================
extern "C" void kernel_launch(void* const* d_in, const int* in_sizes, int n_in,
                              void* d_out, int out_size, void* d_ws, size_t ws_size,
                              hipStream_t stream) {
  (void)in_sizes; (void)n_in; (void)out_size; (void)ws_size;
  const float* x           = (const float*)d_in[0];
  const float* slot_memory = (const float*)d_in[1];
  const float* ln_w        = (const float*)d_in[2];
  const float* ln_b        = (const float*)d_in[3];
  const float* w_in        = (const float*)d_in[4];
  const float* w_q         = (const float*)d_in[5];
  const float* w_k         = (const float*)d_in[6];
  const float* w_v         = (const float*)d_in[7];
  const float* w_gate      = (const float*)d_in[8];
  const float* b_gate      = (const float*)d_in[9];
  const float* halt_w1     = (const float*)d_in[10];
  const float* halt_b1     = (const float*)d_in[11];
  const float* halt_w2     = (const float*)d_in[12];
  const float* halt_b2     = (const float*)d_in[13];
  const float* w_out       = (const float*)d_in[14];
  const float* dn_wk       = (const float*)d_in[15];
  const float* dn_wv       = (const float*)d_in[16];
  const float* dn_wb       = (const float*)d_in[17];
  const float* dn_bb       = (const float*)d_in[18];
  const float* dn_lam      = (const float*)d_in[19];
  const float* dn_wo       = (const float*)d_in[20];
  float* ws  = (float*)d_ws;
  float* out = (float*)d_out;

  k0_prep<<<dim3(64), dim3(256), 0, stream>>>(w_q, w_k, dn_lam, dn_wo, ws);
  k0c_prep<<<dim3(128), dim3(256), 0, stream>>>(w_v, dn_wk, dn_wv, w_gate, halt_w1, dn_wb, ws);
  k1_qk<<<dim3(256), dim3(256), 0, stream>>>(x, ln_w, ln_b, w_in, ws);
  k2_main<<<dim3(TB), dim3(512), 0, stream>>>(slot_memory, b_gate,
                                              halt_b1, halt_w2, halt_b2,
                                              dn_bb, dn_wo, ws, out);
  k3_out<<<dim3(128), dim3(256), 0, stream>>>(w_out, ws, out);
}